// Round 7
// baseline (288.226 us; speedup 1.0000x reference)
//
#include <hip/hip_runtime.h>
#include <cstdint>
#include <cstddef>

// ---------------------------------------------------------------------------
// MultiheadSelectiveAttention (B=2, S=2048, D=1024, H=16, dh=64), fp32 in/out.
//   k_cast_all: X,Wq,Wk -> hi/lo bf16; Wv,Wo -> bf16
//   k_mega: XCD-partitioned longest-first work map (QK | VT | corr)
//   k_ln_pack2: LN(Q),LN(K); head-0 cols += Dlt(2 planes) -> bf16 packs
//   k_s0: head-0 scores, single-staged 4-tile LDS (64KB), 96 MFMAs/block
//   k_seg_apply: in-place S -> -F*log2e, 32-row segments
//   k_attn: SPLIT-K flash attention, 3-buffer 2-deep K/V pipeline with
//           counted vmcnt(8) + raw s_barrier (loads stay in flight across
//           barriers; only the 2-iters-old stage is forced). Last 2 iters
//           peel to a conservative __syncthreads() epilogue. permlane
//           P-relayout, z-init MFMA, uniform diag branch, cvt_pk packing.
//           NOTE: launch_bounds(256,4); (256,5) caused scratch spills (r4).
//   k_comb: sums the two partials per long tile, normalizes, writes bf16
//   k_gemm_nt64: out = Obf @ Wo^T (BK=64, swizzled)
// ---------------------------------------------------------------------------

typedef unsigned short u16;
typedef __attribute__((ext_vector_type(8))) __bf16 bf16x8;
typedef __attribute__((ext_vector_type(4))) float f32x4;
typedef __attribute__((ext_vector_type(2))) unsigned int uint2v;

#define D_MODEL 1024
#define N_HEADS 16
#define BATCH   2
#define SEQ     2048
#define D_HEAD  64
#define ROWS    (BATCH*SEQ)   /* 4096 */
#define NSEG    64
#define SEGLEN  32
#define LOG2E   1.44269504f

static __device__ __forceinline__ u16 f2bf(float f){
  union { float f; uint32_t u; } v; v.f = f;
  uint32_t r = v.u + 0x7fffu + ((v.u >> 16) & 1u);
  return (u16)(r >> 16);
}
static __device__ __forceinline__ float bf2f(u16 h){
  union { uint32_t u; float f; } v; v.u = ((uint32_t)h) << 16;
  return v.f;
}
static __device__ __forceinline__ uint32_t cvtpk(float lo, float hi){
  uint32_t r;
  asm("v_cvt_pk_bf16_f32 %0, %1, %2" : "=v"(r) : "v"(lo), "v"(hi));
  return r;
}
#define GLDS(gp, lp) __builtin_amdgcn_global_load_lds( \
    (const __attribute__((address_space(1))) void*)(gp), \
    (__attribute__((address_space(3))) void*)(lp), 16, 0, 0)

// ------------------------- merged cast kernel ------------------------------
__global__ void k_cast_all(const float* __restrict__ X,
                           u16* __restrict__ Xhi, u16* __restrict__ Xlo,
                           const float* __restrict__ Wq,
                           u16* __restrict__ Wqh, u16* __restrict__ Wql,
                           const float* __restrict__ Wk,
                           u16* __restrict__ Wkh, u16* __restrict__ Wkl,
                           const float* __restrict__ Wv, u16* __restrict__ Wvb,
                           const float* __restrict__ Wo, u16* __restrict__ Wob){
  int i = blockIdx.x*256 + threadIdx.x;   // float4 index
  if (i < 1572864){                       // split: X | Wq | Wk
    const float* src; u16 *dh, *dl; int base;
    if (i < 1048576){ src = X;  dh = Xhi; dl = Xlo; base = i; }
    else if (i < 1310720){ src = Wq; dh = Wqh; dl = Wql; base = i - 1048576; }
    else { src = Wk; dh = Wkh; dl = Wkl; base = i - 1310720; }
    float4 v = reinterpret_cast<const float4*>(src)[base];
    float vs[4] = {v.x, v.y, v.z, v.w};
    union { u16 s[4]; uint2 u; } uh, ul;
#pragma unroll
    for (int r=0;r<4;++r){
      uh.s[r] = f2bf(vs[r]);
      ul.s[r] = f2bf(vs[r] - bf2f(uh.s[r]));
    }
    reinterpret_cast<uint2*>(dh)[base] = uh.u;
    reinterpret_cast<uint2*>(dl)[base] = ul.u;
  } else {                                // plain: Wv | Wo
    const float* src; u16* dst; int base;
    if (i < 1835008){ src = Wv; dst = Wvb; base = i - 1572864; }
    else { src = Wo; dst = Wob; base = i - 1835008; }
    float4 v = reinterpret_cast<const float4*>(src)[base];
    float vs[4] = {v.x, v.y, v.z, v.w};
    union { u16 s[4]; uint2 u; } uh;
#pragma unroll
    for (int r=0;r<4;++r) uh.s[r] = f2bf(vs[r]);
    reinterpret_cast<uint2*>(dst)[base] = uh.u;
  }
}

// ---- mega: XCD-partitioned longest-first: QK | VT | corr, BK=64 swizzled --
__global__ __launch_bounds__(256) void k_mega(
    const u16* __restrict__ Xhi, const u16* __restrict__ Xlo,
    const u16* __restrict__ Wh,  const u16* __restrict__ Wl,
    const u16* __restrict__ Wvb,
    float* __restrict__ C, float* __restrict__ Dlt, u16* __restrict__ Vt)
{
  __shared__ __align__(16) u16 smem[16384];   // 32 KB
  const int xj = blockIdx.x & 7, q = blockIdx.x >> 3;   // q: 0..143
  int section, idx;
  if (q < 64)      { section = 0; idx = xj*64 + q; }       // QK (longest, first)
  else if (q < 128){ section = 1; idx = xj*64 + (q-64); }  // VT
  else             { section = 2; idx = xj*16 + (q-128); } // corr (shortest)
  const int tid = threadIdx.x, wv = tid>>6, ln = tid&63;
  const int lane15 = ln&15, quad = ln>>4;
  const int wm = wv&1, wn = wv>>1;
  const int g = ln&7, sr = ln>>3;           // staging lane coords
  const int fs = lane15 & 7;                // fragment swizzle key
  f32x4 z = {0.f,0.f,0.f,0.f};
  u16* As = smem;                           // 128x64 (8192 u16)
  u16* Bs = smem + 8192;

  if (section == 2){
    // ---- head-0 correction: plane cz: Xhi@Wlo^T (cz=0) / Xlo@Whi^T (cz=1) -
    const int cx = idx & 1;             // Q / K col-group
    const int cy = (idx >> 1) & 31;     // row tile
    const int cz = idx >> 6;            // pass -> its own output plane
    const size_t rowBase = (size_t)cy*128;
    const size_t wbase = cx ? (size_t)1024*1024 : 0;
    const u16* Ap = cz ? Xlo : Xhi;
    const u16* Bp = (cz ? Wh : Wl) + wbase;
    f32x4 acc[4][2];
#pragma unroll
    for (int i=0;i<4;++i){ acc[i][0] = z; acc[i][1] = z; }
    for (int kt = 0; kt < 16; ++kt) {
      __syncthreads();
#pragma unroll
      for (int c = 0; c < 4; ++c) {
        int chunk = wv*4 + c, r = chunk*8 + sr;
        GLDS(Ap + (rowBase + r)*1024 + kt*64 + (g^sr)*8, As + chunk*512);
      }
#pragma unroll
      for (int c = 0; c < 2; ++c) {
        int chunk = wv*2 + c, r = chunk*8 + sr;
        GLDS(Bp + (size_t)r*1024 + kt*64 + (g^sr)*8, Bs + chunk*512);
      }
      __syncthreads();
#pragma unroll
      for (int k2=0;k2<2;++k2){
        bf16x8 af[4], bfb[2];
#pragma unroll
        for (int t=0;t<4;++t)
          af[t]  = *reinterpret_cast<const bf16x8*>(As + (wm*64 + t*16 + lane15)*64 + (((k2*4+quad)^fs)*8));
#pragma unroll
        for (int t=0;t<2;++t)
          bfb[t] = *reinterpret_cast<const bf16x8*>(Bs + (wn*32 + t*16 + lane15)*64 + (((k2*4+quad)^fs)*8));
#pragma unroll
        for (int i=0;i<4;++i)
#pragma unroll
          for (int j=0;j<2;++j)
            acc[i][j] = __builtin_amdgcn_mfma_f32_16x16x32_bf16(af[i], bfb[j], acc[i][j], 0,0,0);
      }
    }
    float* Dp = Dlt + (size_t)cz*ROWS*128;
#pragma unroll
    for (int i=0;i<4;++i){
      size_t row = rowBase + wm*64 + i*16 + quad*4;
#pragma unroll
      for (int j=0;j<2;++j){
        size_t col = (size_t)cx*64 + wn*32 + j*16 + lane15;
#pragma unroll
        for (int r=0;r<4;++r)
          Dp[(row+r)*128 + col] = acc[i][j][r];
      }
    }
  } else if (section == 0){
    // ---------------- QK projection: 128x128 tile, 1-pass ------------------
    const size_t rowBase = (size_t)(idx>>4)*128, colBase = (size_t)(idx&15)*128;
    f32x4 acc[4][4];
#pragma unroll
    for (int i=0;i<4;++i)
#pragma unroll
      for (int j=0;j<4;++j) acc[i][j] = z;
    for (int kt = 0; kt < 16; ++kt) {
      __syncthreads();
#pragma unroll
      for (int c = 0; c < 4; ++c) {
        int chunk = wv*4 + c, r = chunk*8 + sr;
        GLDS(Xhi + (rowBase + r)*1024 + kt*64 + (g^sr)*8, As + chunk*512);
        GLDS(Wh  + (colBase + r)*1024 + kt*64 + (g^sr)*8, Bs + chunk*512);
      }
      __syncthreads();
#pragma unroll
      for (int k2=0;k2<2;++k2){
        bf16x8 af[4], bfb[4];
#pragma unroll
        for (int t=0;t<4;++t){
          af[t]  = *reinterpret_cast<const bf16x8*>(As + (wm*64 + t*16 + lane15)*64 + (((k2*4+quad)^fs)*8));
          bfb[t] = *reinterpret_cast<const bf16x8*>(Bs + (wn*64 + t*16 + lane15)*64 + (((k2*4+quad)^fs)*8));
        }
#pragma unroll
        for (int i=0;i<4;++i)
#pragma unroll
          for (int j=0;j<4;++j)
            acc[i][j] = __builtin_amdgcn_mfma_f32_16x16x32_bf16(af[i], bfb[j], acc[i][j], 0,0,0);
      }
    }
#pragma unroll
    for (int i=0;i<4;++i){
      size_t row = rowBase + wm*64 + i*16 + quad*4;
#pragma unroll
      for (int j=0;j<4;++j){
        size_t col = colBase + wn*64 + j*16 + lane15;
#pragma unroll
        for (int r=0;r<4;++r)
          C[(row+r)*2048 + col] = acc[i][j][r];
      }
    }
  } else {
    // ------- V projection with fused V^T bf16 epilogue (LDS transpose) -----
    const int bx = idx & 15, by = idx >> 4;
    const size_t rowBase = (size_t)by*128, colBase = (size_t)bx*64;
    f32x4 acc[4][2];
#pragma unroll
    for (int i=0;i<4;++i){ acc[i][0] = z; acc[i][1] = z; }
    for (int kt = 0; kt < 16; ++kt) {
      __syncthreads();
#pragma unroll
      for (int c = 0; c < 4; ++c) {
        int chunk = wv*4 + c, r = chunk*8 + sr;
        GLDS(Xhi + (rowBase + r)*1024 + kt*64 + (g^sr)*8, As + chunk*512);
      }
#pragma unroll
      for (int c = 0; c < 2; ++c) {
        int chunk = wv*2 + c, r = chunk*8 + sr;
        GLDS(Wvb + (colBase + r)*1024 + kt*64 + (g^sr)*8, Bs + chunk*512);
      }
      __syncthreads();
#pragma unroll
      for (int k2=0;k2<2;++k2){
        bf16x8 af[4], bfb[2];
#pragma unroll
        for (int t=0;t<4;++t)
          af[t]  = *reinterpret_cast<const bf16x8*>(As + (wm*64 + t*16 + lane15)*64 + (((k2*4+quad)^fs)*8));
#pragma unroll
        for (int t=0;t<2;++t)
          bfb[t] = *reinterpret_cast<const bf16x8*>(Bs + (wn*32 + t*16 + lane15)*64 + (((k2*4+quad)^fs)*8));
#pragma unroll
        for (int i=0;i<4;++i)
#pragma unroll
          for (int j=0;j<2;++j)
            acc[i][j] = __builtin_amdgcn_mfma_f32_16x16x32_bf16(af[i], bfb[j], acc[i][j], 0,0,0);
      }
    }
    // transpose epilogue: stage bf16 tile as [d 64][n 128] (stride 136)
    __syncthreads();
#pragma unroll
    for (int i=0;i<4;++i){
      int nl = wm*64 + i*16 + quad*4;
#pragma unroll
      for (int j=0;j<2;++j){
        int dl = wn*32 + j*16 + lane15;
#pragma unroll
        for (int r=0;r<4;++r)
          smem[dl*136 + nl + r] = f2bf(acc[i][j][r]);
      }
    }
    __syncthreads();
    const int b = by >> 4;
    const int n0 = (by & 15) * 128;
    const int bh = b*N_HEADS + bx;
    const int d = tid >> 2, seg = tid & 3;
    u16* dst = Vt + ((size_t)(bh*64 + d))*SEQ + n0 + seg*32;
    const u16* srcl = smem + d*136 + seg*32;
#pragma unroll
    for (int k=0;k<4;++k)
      *reinterpret_cast<uint4*>(dst + k*8) = *reinterpret_cast<const uint4*>(srcl + k*8);
  }
}

// --------- merged LN for Q and K + bf16 head packs (+ head0 corr) ----------
__global__ __launch_bounds__(256) void k_ln_pack2(
    const float* __restrict__ C, const float* __restrict__ Dlt,
    const float* __restrict__ gq, const float* __restrict__ bq,
    const float* __restrict__ gk, const float* __restrict__ bk,
    u16* __restrict__ Qh, u16* __restrict__ Kh,
    u16* __restrict__ Q0l, u16* __restrict__ K0l)
{
  const int row = blockIdx.x;
  const int tid = threadIdx.x;
  const float* cr = C + (size_t)row*2048;
  float4 vq = reinterpret_cast<const float4*>(cr)[tid];
  float4 vk = reinterpret_cast<const float4*>(cr)[256 + tid];
  const int h = tid >> 4;
  if (h == 0){
    const float* D0 = Dlt + (size_t)row*128;
    const float* D1 = Dlt + (size_t)ROWS*128 + (size_t)row*128;
    float4 a0 = reinterpret_cast<const float4*>(D0)[tid&15];
    float4 a1 = reinterpret_cast<const float4*>(D1)[tid&15];
    vq.x+=a0.x+a1.x; vq.y+=a0.y+a1.y; vq.z+=a0.z+a1.z; vq.w+=a0.w+a1.w;
    float4 b0 = reinterpret_cast<const float4*>(D0 + 64)[tid&15];
    float4 b1 = reinterpret_cast<const float4*>(D1 + 64)[tid&15];
    vk.x+=b0.x+b1.x; vk.y+=b0.y+b1.y; vk.z+=b0.z+b1.z; vk.w+=b0.w+b1.w;
  }
  float sq  = vq.x+vq.y+vq.z+vq.w;
  float s2q = vq.x*vq.x+vq.y*vq.y+vq.z*vq.z+vq.w*vq.w;
  float sk  = vk.x+vk.y+vk.z+vk.w;
  float s2k = vk.x*vk.x+vk.y*vk.y+vk.z*vk.z+vk.w*vk.w;
#pragma unroll
  for (int o=32;o;o>>=1){
    sq += __shfl_xor(sq,o);  s2q += __shfl_xor(s2q,o);
    sk += __shfl_xor(sk,o);  s2k += __shfl_xor(s2k,o);
  }
  __shared__ float red[4][4];
  if ((tid&63)==0){
    red[tid>>6][0]=sq; red[tid>>6][1]=s2q; red[tid>>6][2]=sk; red[tid>>6][3]=s2k;
  }
  __syncthreads();
  sq  = red[0][0]+red[1][0]+red[2][0]+red[3][0];
  s2q = red[0][1]+red[1][1]+red[2][1]+red[3][1];
  sk  = red[0][2]+red[1][2]+red[2][2]+red[3][2];
  s2k = red[0][3]+red[1][3]+red[2][3]+red[3][3];
  const float muq = sq*(1.f/D_MODEL);
  const float rsq = rsqrtf(s2q*(1.f/D_MODEL) - muq*muq + 1e-5f);
  const float muk = sk*(1.f/D_MODEL);
  const float rsk = rsqrtf(s2k*(1.f/D_MODEL) - muk*muk + 1e-5f);
  const int b = row >> 11, n = row & (SEQ-1);
  const int d0 = (tid & 15)*4;
  float4 gqv = reinterpret_cast<const float4*>(gq)[tid];
  float4 bqv = reinterpret_cast<const float4*>(bq)[tid];
  float4 gkv = reinterpret_cast<const float4*>(gk)[tid];
  float4 bkv = reinterpret_cast<const float4*>(bk)[tid];
  float xq[4] = {vq.x,vq.y,vq.z,vq.w}, xk[4] = {vk.x,vk.y,vk.z,vk.w};
  float gQ[4] = {gqv.x,gqv.y,gqv.z,gqv.w}, bQ[4] = {bqv.x,bqv.y,bqv.z,bqv.w};
  float gK[4] = {gkv.x,gkv.y,gkv.z,gkv.w}, bK[4] = {bkv.x,bkv.y,bkv.z,bkv.w};
  union { u16 s[4]; uint2 u; } qh, ql, kh, kl;
#pragma unroll
  for (int r=0;r<4;++r){
    float yq = (xq[r]-muq)*rsq*gQ[r] + bQ[r];
    qh.s[r] = f2bf(yq);
    ql.s[r] = f2bf(yq - bf2f(qh.s[r]));
    float yk = (xk[r]-muk)*rsk*gK[r] + bK[r];
    kh.s[r] = f2bf(yk);
    kl.s[r] = f2bf(yk - bf2f(kh.s[r]));
  }
  size_t dst = (((size_t)(b*N_HEADS + h))*SEQ + n)*D_HEAD + d0;
  *reinterpret_cast<uint2*>(Qh + dst) = qh.u;
  *reinterpret_cast<uint2*>(Kh + dst) = kh.u;
  if (h == 0){
    size_t dl = ((size_t)b*SEQ + n)*D_HEAD + d0;
    *reinterpret_cast<uint2*>(Q0l + dl) = ql.u;
    *reinterpret_cast<uint2*>(K0l + dl) = kl.u;
  }
}

// ------ head-0 scores, single-staged 4-tile LDS + 32-row segment sums ------
__global__ __launch_bounds__(256) void k_s0(
    const u16* Qh, const u16* Q0l, const u16* Kh, const u16* K0l,
    float* __restrict__ S0, float* __restrict__ seg)
{
  const int b = blockIdx.z;
  const int bm = blockIdx.y;  // j (query-row) 128-tile -> segments 4bm..4bm+3
  const int bn = blockIdx.x;  // m (key-col) tile
  const int tid = threadIdx.x;
  if (bn > bm){               // above diagonal: S never read there; seg = 0
    for (int t = tid; t < 512; t += 256)
      seg[((size_t)b*NSEG + bm*4 + (t>>7))*SEQ + bn*128 + (t&127)] = 0.f;
    return;
  }
  float* Sb = S0 + (size_t)b*SEQ*SEQ;
  __shared__ __align__(16) u16 smem[4*8192];   // Qhi|Qlo|Khi|Klo, 64 KB
  const int wv = tid>>6, ln = tid&63;
  const int lane15 = ln&15, quad = ln>>4;
  const int wm = wv&1, wn = wv>>1;
  const int g = ln&7, sr = ln>>3;
  const int fs = lane15 & 7;
  const size_t rowBase = (size_t)bm*128, colBase = (size_t)bn*128;
  const u16* srcs[4] = {
    Qh  + ((size_t)b*N_HEADS*SEQ + rowBase)*D_HEAD,   // head-0 Q hi
    Q0l + ((size_t)b*SEQ + rowBase)*D_HEAD,
    Kh  + ((size_t)b*N_HEADS*SEQ + colBase)*D_HEAD,   // head-0 K hi
    K0l + ((size_t)b*SEQ + colBase)*D_HEAD };
#pragma unroll
  for (int t=0;t<4;++t){
#pragma unroll
    for (int c=0;c<4;++c){
      int chunk = wv*4 + c, r = chunk*8 + sr;
      GLDS(srcs[t] + (size_t)r*64 + (g^sr)*8, smem + t*8192 + chunk*512);
    }
  }
  __syncthreads();
  f32x4 acc[4][4];
  f32x4 z = {0.f,0.f,0.f,0.f};
#pragma unroll
  for (int i=0;i<4;++i)
#pragma unroll
    for (int j=0;j<4;++j) acc[i][j] = z;
  const int Aidx[3] = {0, 0, 1};    // Qhi,Qhi,Qlo
  const int Bidx[3] = {2, 3, 2};    // Khi,Klo,Khi
#pragma unroll
  for (int p = 0; p < 3; ++p){
    const u16* At = smem + Aidx[p]*8192;
    const u16* Bt = smem + Bidx[p]*8192;
#pragma unroll
    for (int k2=0;k2<2;++k2){
      bf16x8 af[4], bfb[4];
#pragma unroll
      for (int t=0;t<4;++t){
        af[t]  = *reinterpret_cast<const bf16x8*>(At + (wm*64 + t*16 + lane15)*64 + (((k2*4+quad)^fs)*8));
        bfb[t] = *reinterpret_cast<const bf16x8*>(Bt + (wn*64 + t*16 + lane15)*64 + (((k2*4+quad)^fs)*8));
      }
#pragma unroll
      for (int i=0;i<4;++i)
#pragma unroll
        for (int j=0;j<4;++j)
          acc[i][j] = __builtin_amdgcn_mfma_f32_16x16x32_bf16(af[i], bfb[j], acc[i][j], 0,0,0);
    }
  }
  float csum[2][4] = {{0.f,0.f,0.f,0.f},{0.f,0.f,0.f,0.f}};
#pragma unroll
  for (int i=0;i<4;++i){
#pragma unroll
    for (int j=0;j<4;++j){
#pragma unroll
      for (int r=0;r<4;++r){
        int jg = (int)rowBase + wm*64 + i*16 + quad*4 + r;
        int mg = (int)colBase + wn*64 + j*16 + lane15;
        float l = acc[i][j][r]*0.125f;
        float s = (mg >= 1 && mg < jg) ? fmaxf(l, 0.f) : 0.f;
        Sb[(size_t)jg*SEQ + mg] = s;
        csum[i>>1][j] += s;
      }
    }
  }
  __syncthreads();                 // tiles consumed; reuse LDS for cs
  float* cs = (float*)smem;        // [4][128]
#pragma unroll
  for (int h2=0;h2<2;++h2){
#pragma unroll
    for (int j=0;j<4;++j){
      float v = csum[h2][j];
      v += __shfl_xor(v, 16);
      v += __shfl_xor(v, 32);
      if (ln < 16) cs[(wm*2 + h2)*128 + wn*64 + j*16 + ln] = v;
    }
  }
  __syncthreads();
  for (int t = tid; t < 512; t += 256)
    seg[((size_t)b*NSEG + bm*4 + (t>>7))*SEQ + bn*128 + (t&127)] = cs[t];
}

// --- in place: S -> -F*log2e; 32-row segments; prefix from seg sums --------
__global__ void k_seg_apply(float* __restrict__ SF, const float* __restrict__ seg){
  int m = blockIdx.x*256 + threadIdx.x;
  int s = blockIdx.y, b = blockIdx.z;
  const float* sb = seg + (size_t)b*NSEG*SEQ;
  float run = 0.f;
  for (int t=0; t<s; ++t) run += sb[(size_t)t*SEQ + m];   // independent loads
  float* Sb = SF + (size_t)b*SEQ*SEQ;
  const int j0 = s*SEGLEN;
#pragma unroll 8
  for (int i=0;i<SEGLEN;++i){
    size_t idx = (size_t)(j0 + i)*SEQ + m;
    float t = Sb[idx];
    Sb[idx] = -run*LOG2E;
    run += (j0 + i > m) ? t : 0.f;
  }
}

// ------------- split-K flash attention, fixed-max softmax ------------------
// Work item table (per bh): 48 entries sorted by length descending.
// code < 64: long tile, nt = code>>1 (16..31), seg = code&1, key range split
//            at half = (nt+2)>>1; writes f32 partials (exact-additive since
//            softmax offset F is fixed per row, no running max).
// code >= 64: short tile nt = code-64 (0..15), full range, direct bf16 write.
__constant__ unsigned char WMAP[48] = {
  62,63,60,79,
  61,58,59,56,78,
  57,54,55,52,77,
  53,50,51,48,76,
  49,46,47,44,75,
  45,42,43,40,74,
  41,38,39,36,73,
  37,34,35,32,72,
  33,71,
  70,69,68,67,66,65,64};

__global__ __launch_bounds__(256, 4) void k_attn(
    const u16* __restrict__ Qh, const u16* __restrict__ Kh,
    const u16* __restrict__ Vt, const float* __restrict__ F,
    u16* __restrict__ Ob, float* __restrict__ Opart, float* __restrict__ Ps)
{
  __shared__ __align__(16) u16 Ks[3][64*64];   // 3-buffer, 2-deep prefetch
  __shared__ __align__(16) u16 Vs[3][64*64];   // 48 KB total
  const int w = blockIdx.x;
  const int bh = w & 31, b = bh >> 4, h = bh & 15;
  const int item = (int)WMAP[w >> 5];
  int nt, mt0, mt1, segi;
  if (item >= 64){ nt = item - 64; segi = 0; mt0 = 0; mt1 = nt; }
  else {
    nt = item >> 1; segi = item & 1;
    const int half = (nt + 2) >> 1;           // ceil((nt+1)/2)
    mt0 = segi ? half : 0;
    mt1 = segi ? nt : (half - 1);
  }
  const bool partial = (item < 64);
  const int tid = threadIdx.x, wv = tid>>6, ln = tid&63;
  const int lane15 = ln&15, quad = ln>>4;
  const u16* Qbh = Qh + ((size_t)(b*N_HEADS + h))*SEQ*D_HEAD;
  const u16* Kbh = Kh + ((size_t)(b*N_HEADS + h))*SEQ*D_HEAD;
  const u16* Vbh = Vt + ((size_t)(b*N_HEADS + h))*D_HEAD*SEQ;
  const int n_loc = wv*16 + lane15;
  const int n_g = nt*64 + n_loc;
  const float* Frow = F + (size_t)b*SEQ*SEQ + (size_t)n_g*SEQ;
  const int swz = (ln&7) ^ ((ln>>3)&7);
  const int fswz = lane15 & 7;
  const int srow = ln>>3;

  bf16x8 qf[2];
#pragma unroll
  for (int kt=0; kt<2; ++kt)
    qf[kt] = *reinterpret_cast<const bf16x8*>(Qbh + (size_t)n_g*D_HEAD + kt*32 + quad*8);

  f32x4 z = {0.f,0.f,0.f,0.f};
  f32x4 psum = z;
  f32x4 acc_o[4];
#pragma unroll
  for (int no=0;no<4;++no) acc_o[no] = z;

  auto stage = [&](int mt, int buf){
#pragma unroll
    for (int c=0;c<2;++c){
      int chunk = wv*2 + c;
      int r = chunk*8 + srow;
      GLDS(Kbh + (size_t)(mt*64 + r)*D_HEAD + swz*8, &Ks[buf][chunk*512]);
      GLDS(Vbh + (size_t)r*SEQ + mt*64 + swz*8,      &Vs[buf][chunk*512]);
    }
  };
  const float c1 = 0.125f*LOG2E;
  f32x4 fv[4], fvn[4];

  // one iteration of compute on buffer bi with F offsets in fv
  auto compute = [&](int mt, int bi){
    f32x4 accs[4];
    __builtin_amdgcn_s_setprio(1);
#pragma unroll
    for (int ms=0; ms<4; ++ms){
      bf16x8 a = *reinterpret_cast<const bf16x8*>(
          &Ks[bi][(ms*16 + lane15)*64 + ((quad ^ fswz) * 8)]);
      accs[ms] = __builtin_amdgcn_mfma_f32_16x16x32_bf16(a, qf[0], z, 0,0,0);
    }
#pragma unroll
    for (int ms=0; ms<4; ++ms){
      bf16x8 a = *reinterpret_cast<const bf16x8*>(
          &Ks[bi][(ms*16 + lane15)*64 + (((4 + quad) ^ fswz) * 8)]);
      accs[ms] = __builtin_amdgcn_mfma_f32_16x16x32_bf16(a, qf[1], accs[ms], 0,0,0);
    }
    __builtin_amdgcn_s_setprio(0);
    uint32_t pw[4][2];
    if (mt == nt){
#pragma unroll
      for (int ms=0; ms<4; ++ms){
        const int ml = ms*16 + quad*4;
        float l0 = fmaf(accs[ms][0], c1, fv[ms][0]);
        float l1 = fmaf(accs[ms][1], c1, fv[ms][1]);
        float l2 = fmaf(accs[ms][2], c1, fv[ms][2]);
        float l3 = fmaf(accs[ms][3], c1, fv[ms][3]);
        if (ml + 0 > n_loc) l0 = -1e30f;
        if (ml + 1 > n_loc) l1 = -1e30f;
        if (ml + 2 > n_loc) l2 = -1e30f;
        if (ml + 3 > n_loc) l3 = -1e30f;
        float p0 = __builtin_amdgcn_exp2f(l0);
        float p1 = __builtin_amdgcn_exp2f(l1);
        float p2 = __builtin_amdgcn_exp2f(l2);
        float p3 = __builtin_amdgcn_exp2f(l3);
        psum[0]+=p0; psum[1]+=p1; psum[2]+=p2; psum[3]+=p3;
        pw[ms][0] = cvtpk(p0, p1);
        pw[ms][1] = cvtpk(p2, p3);
      }
    } else {
#pragma unroll
      for (int ms=0; ms<4; ++ms){
        float p0 = __builtin_amdgcn_exp2f(fmaf(accs[ms][0], c1, fv[ms][0]));
        float p1 = __builtin_amdgcn_exp2f(fmaf(accs[ms][1], c1, fv[ms][1]));
        float p2 = __builtin_amdgcn_exp2f(fmaf(accs[ms][2], c1, fv[ms][2]));
        float p3 = __builtin_amdgcn_exp2f(fmaf(accs[ms][3], c1, fv[ms][3]));
        psum[0]+=p0; psum[1]+=p1; psum[2]+=p2; psum[3]+=p3;
        pw[ms][0] = cvtpk(p0, p1);
        pw[ms][1] = cvtpk(p2, p3);
      }
    }
    __builtin_amdgcn_s_setprio(1);
#pragma unroll
    for (int kt=0; kt<2; ++kt){
      union { uint32_t u[4]; bf16x8 v; } pa;
#pragma unroll
      for (int pr=0; pr<2; ++pr){
        uint2v s32 = __builtin_amdgcn_permlane32_swap(
            pw[2*kt][pr], pw[2*kt+1][pr], false, false);
        uint2v s16 = __builtin_amdgcn_permlane16_swap(s32.x, s32.y, false, false);
        pa.u[pr]   = s16.x;
        pa.u[2+pr] = s16.y;
      }
#pragma unroll
      for (int no=0; no<4; ++no){
        int d = no*16 + lane15;
        bf16x8 vb = *reinterpret_cast<const bf16x8*>(
            &Vs[bi][d*64 + (((kt*4 + quad) ^ (d&7)) * 8)]);
        acc_o[no] = __builtin_amdgcn_mfma_f32_16x16x32_bf16(pa.v, vb, acc_o[no], 0,0,0);
      }
    }
    __builtin_amdgcn_s_setprio(0);
  };

  // prologue: S(mt0) oldest, then F(mt0), then S(mt0+1) if it exists
  stage(mt0, 0);
#pragma unroll
  for (int ms=0; ms<4; ++ms)
    fvn[ms] = *reinterpret_cast<const f32x4*>(Frow + mt0*64 + ms*16 + quad*4);
  if (mt0 < mt1) stage(mt0+1, 1);

  // steady-state pipelined loop (runs when >= 3 iterations): per wave,
  // vmcnt(8) forces only stage(mt) (2 phases old); the newest 8 ops
  // (F(mt) + stage(mt+1)) stay in flight across the raw barrier.
  int mt = mt0;
  for (; mt <= mt1 - 2; ++mt){
    asm volatile("s_waitcnt vmcnt(8)" ::: "memory");
    __builtin_amdgcn_sched_barrier(0);
    __builtin_amdgcn_s_barrier();
    __builtin_amdgcn_sched_barrier(0);
#pragma unroll
    for (int ms=0; ms<4; ++ms) fv[ms] = fvn[ms];   // waits F(mt) only
    const float* Fr1 = Frow + (mt+1)*64;
#pragma unroll
    for (int ms=0; ms<4; ++ms)
      fvn[ms] = *reinterpret_cast<const f32x4*>(Fr1 + ms*16 + quad*4);
    stage(mt+2, (mt+2-mt0) % 3);
    compute(mt, (mt-mt0) % 3);
  }
  // conservative epilogue (last <=2 iterations; whole block for short tiles)
  for (; mt <= mt1; ++mt){
    __syncthreads();                    // full drain: everything ready
#pragma unroll
    for (int ms=0; ms<4; ++ms) fv[ms] = fvn[ms];
    if (mt < mt1){
      const float* Fr1 = Frow + (mt+1)*64;
#pragma unroll
      for (int ms=0; ms<4; ++ms)
        fvn[ms] = *reinterpret_cast<const f32x4*>(Fr1 + ms*16 + quad*4);
    }
    compute(mt, (mt-mt0) % 3);
  }

  float s = (psum[0]+psum[1]) + (psum[2]+psum[3]);
  s += __shfl_xor(s, 16);
  s += __shfl_xor(s, 32);
  if (partial){
    // exact-additive partial: raw acc_o (f32) + per-row psum
    const size_t pb = (size_t)(bh*16 + (nt - 16))*2 + segi;
    float* Op = Opart + pb*4096;
    if (quad == 0) Ps[pb*64 + wv*16 + lane15] = s;
#pragma unroll
    for (int no=0; no<4; ++no)
#pragma unroll
      for (int r=0;r<4;++r)
        Op[(wv*16 + quad*4 + r)*64 + no*16 + lane15] = acc_o[no][r];
  } else {
    f32x4 inv;
#pragma unroll
    for (int r=0;r<4;++r)
      inv[r] = __builtin_amdgcn_rcpf(__shfl(s, quad*4 + r));
#pragma unroll
    for (int no=0; no<4; ++no){
#pragma unroll
      for (int r=0;r<4;++r){
        float o = acc_o[no][r] * inv[r];
        int row = nt*64 + wv*16 + quad*4 + r;
        Ob[((size_t)(b*SEQ + row))*D_MODEL + h*64 + no*16 + lane15] = f2bf(o);
      }
    }
  }
}

// --------- combine two key-segment partials per long tile -> bf16 ----------
__global__ __launch_bounds__(256) void k_comb(
    const float* __restrict__ Opart, const float* __restrict__ Ps,
    u16* __restrict__ Ob)
{
  const int t = blockIdx.x;            // bh*16 + (nt-16), 0..511
  const int bh = t >> 4, b = bh >> 4, h = bh & 15;
  const int nt = (t & 15) + 16;
  const int tid = threadIdx.x;
  const int row = tid >> 2, c0 = (tid & 3) * 16;
  const float* P0 = Opart + (size_t)t*2*4096 + row*64 + c0;
  const float* P1 = P0 + 4096;
  const float s = Ps[(size_t)t*128 + row] + Ps[(size_t)t*128 + 64 + row];
  const float inv = __builtin_amdgcn_rcpf(s);
  union { u16 us[16]; uint4 u[2]; } o;
#pragma unroll
  for (int g2=0; g2<4; ++g2){
    float4 a = reinterpret_cast<const float4*>(P0)[g2];
    float4 c = reinterpret_cast<const float4*>(P1)[g2];
    o.us[g2*4+0] = f2bf((a.x + c.x) * inv);
    o.us[g2*4+1] = f2bf((a.y + c.y) * inv);
    o.us[g2*4+2] = f2bf((a.z + c.z) * inv);
    o.us[g2*4+3] = f2bf((a.w + c.w) * inv);
  }
  u16* dst = Ob + ((size_t)(b*SEQ + nt*64 + row))*D_MODEL + h*64 + c0;
  reinterpret_cast<uint4*>(dst)[0] = o.u[0];
  reinterpret_cast<uint4*>(dst)[1] = o.u[1];
}

// ------------- NT GEMM, 128x64 tile, BK=64 swizzled (O-proj) ---------------
__global__ __launch_bounds__(256) void k_gemm_nt64(
    const u16* __restrict__ A0, const u16* __restrict__ B0,
    float* __restrict__ C, int N, int K)
{
  __shared__ __align__(16) u16 As[8192];   // 128x64
  __shared__ __align__(16) u16 Bs[4096];   // 64x64
  const int tid = threadIdx.x, wv = tid>>6, ln = tid&63;
  const int lane15 = ln&15, quad = ln>>4;
  const int wm = wv&1, wn = wv>>1;
  const int g = ln&7, sr = ln>>3;
  const int fs = lane15 & 7;
  const size_t rowBase = (size_t)blockIdx.y*128, colBase = (size_t)blockIdx.x*64;
  f32x4 acc[4][2];
  f32x4 z = {0.f,0.f,0.f,0.f};
#pragma unroll
  for (int i=0;i<4;++i){ acc[i][0] = z; acc[i][1] = z; }
  const int ktiles = K >> 6;
  for (int kt = 0; kt < ktiles; ++kt) {
    __syncthreads();
#pragma unroll
    for (int c = 0; c < 4; ++c) {
      int chunk = wv*4 + c, r = chunk*8 + sr;
      GLDS(A0 + (rowBase + r)*K + kt*64 + (g^sr)*8, As + chunk*512);
    }
#pragma unroll
    for (int c = 0; c < 2; ++c) {
      int chunk = wv*2 + c, r = chunk*8 + sr;
      GLDS(B0 + (colBase + r)*K + kt*64 + (g^sr)*8, Bs + chunk*512);
    }
    __syncthreads();
#pragma unroll
    for (int k2=0;k2<2;++k2){
      bf16x8 af[4], bfb[2];
#pragma unroll
      for (int t=0;t<4;++t)
        af[t]  = *reinterpret_cast<const bf16x8*>(As + (wm*64 + t*16 + lane15)*64 + (((k2*4+quad)^fs)*8));
#pragma unroll
      for (int t=0;t<2;++t)
        bfb[t] = *reinterpret_cast<const bf16x8*>(Bs + (wn*32 + t*16 + lane15)*64 + (((k2*4+quad)^fs)*8));
#pragma unroll
      for (int i=0;i<4;++i)
#pragma unroll
        for (int j=0;j<2;++j)
          acc[i][j] = __builtin_amdgcn_mfma_f32_16x16x32_bf16(af[i], bfb[j], acc[i][j], 0,0,0);
    }
  }
#pragma unroll
  for (int i=0;i<4;++i){
    size_t row = rowBase + wm*64 + i*16 + quad*4;
#pragma unroll
    for (int j=0;j<2;++j){
      size_t col = colBase + wn*32 + j*16 + lane15;
#pragma unroll
      for (int r=0;r<4;++r)
        C[(row+r)*N + col] = acc[i][j][r];
    }
  }
}

// ------------------------------- launcher ----------------------------------
extern "C" void kernel_launch(void* const* d_in, const int* in_sizes, int n_in,
                              void* d_out, int out_size, void* d_ws, size_t ws_size,
                              hipStream_t stream)
{
  (void)in_sizes; (void)n_in; (void)out_size; (void)ws_size;
  const float* X  = (const float*)d_in[0];
  const float* Wq = (const float*)d_in[1];
  const float* Wk = (const float*)d_in[2];
  const float* Wv = (const float*)d_in[3];
  const float* Wo = (const float*)d_in[4];
  const float* gq = (const float*)d_in[5];
  const float* bq = (const float*)d_in[6];
  const float* gk = (const float*)d_in[7];
  const float* bk = (const float*)d_in[8];
  float* out = (float*)d_out;

  char* ws = (char*)d_ws;
  size_t off = 0;
  auto alloc = [&](size_t bytes)->char*{
    char* p = ws + off; off += (bytes + 255) & ~(size_t)255; return p;
  };
  u16* Xhi  = (u16*)alloc((size_t)ROWS*D_MODEL*2);
  u16* Xlo  = (u16*)alloc((size_t)ROWS*D_MODEL*2);
  u16* Wqkh = (u16*)alloc((size_t)2*D_MODEL*D_MODEL*2);  // [Wq;Wk] hi
  u16* Wqkl = (u16*)alloc((size_t)2*D_MODEL*D_MODEL*2);  // [Wq;Wk] lo
  u16* Wvb  = (u16*)alloc((size_t)D_MODEL*D_MODEL*2);
  u16* Wob  = (u16*)alloc((size_t)D_MODEL*D_MODEL*2);
  u16* Qhp  = (u16*)alloc((size_t)BATCH*N_HEADS*SEQ*D_HEAD*2);
  u16* Khp  = (u16*)alloc((size_t)BATCH*N_HEADS*SEQ*D_HEAD*2);
  u16* Q0l  = (u16*)alloc((size_t)BATCH*SEQ*D_HEAD*2);
  u16* K0l  = (u16*)alloc((size_t)BATCH*SEQ*D_HEAD*2);
  u16* Vtp  = (u16*)alloc((size_t)BATCH*N_HEADS*D_HEAD*SEQ*2);
  u16* Obf  = (u16*)alloc((size_t)ROWS*D_MODEL*2);
  float* Dlt = (float*)alloc((size_t)2*ROWS*128*4);      // head-0 corr planes
  float* Seg = (float*)alloc((size_t)BATCH*NSEG*SEQ*4);  // 1 MB
  float* Opart = (float*)alloc((size_t)512*2*4096*4);    // 16.8 MB partial O
  float* Ps    = (float*)alloc((size_t)512*2*64*4);      // partial psums
  float* SF  = (float*)alloc((size_t)BATCH*SEQ*SEQ*4);   // 33.5 MB
  float* C32 = SF;    // QK-proj fp32 scratch aliases SF (consumed before s0)

  k_cast_all<<<8192, 256, 0, stream>>>(
      X, Xhi, Xlo,
      Wq, Wqkh, Wqkl,
      Wk, Wqkh + (size_t)D_MODEL*D_MODEL, Wqkl + (size_t)D_MODEL*D_MODEL,
      Wv, Wvb, Wo, Wob);
  k_mega<<<1152, 256, 0, stream>>>(Xhi, Xlo, Wqkh, Wqkl, Wvb, C32, Dlt, Vtp);
  k_ln_pack2<<<ROWS, 256, 0, stream>>>(C32, Dlt, gq, bq, gk, bk, Qhp, Khp, Q0l, K0l);
  k_s0<<<dim3(16, 16, BATCH), 256, 0, stream>>>(Qhp, Q0l, Khp, K0l, SF, Seg);
  k_seg_apply<<<dim3(8, NSEG, BATCH), 256, 0, stream>>>(SF, Seg);
  k_attn<<<1536, 256, 0, stream>>>(Qhp, Khp, Vtp, SF, Obf, Opart, Ps);
  k_comb<<<512, 256, 0, stream>>>(Opart, Ps, Obf);
  k_gemm_nt64<<<dim3(16, 32), 256, 0, stream>>>(Obf, Wob, out, D_MODEL, D_MODEL);
}

// Round 8
// 277.238 us; speedup vs baseline: 1.0396x; 1.0396x over previous
//
#include <hip/hip_runtime.h>
#include <cstdint>
#include <cstddef>

// ---------------------------------------------------------------------------
// MultiheadSelectiveAttention (B=2, S=2048, D=1024, H=16, dh=64), fp32 in/out.
//   k_cast_all: X,Wq,Wk -> hi/lo bf16; Wv,Wo -> bf16
//   k_mega: XCD-partitioned longest-first work map (QK | VT | corr)
//   k_ln_pack2: LN(Q),LN(K); head-0 cols += Dlt(2 planes) -> bf16 packs
//   k_s0: head-0 scores, single-staged 4-tile LDS (64KB), 96 MFMAs/block
//   k_segpfx: in-place exclusive prefix over Seg's 64 s-slices (per column)
//   k_seg_apply: in-place S -> -F*log2e, 32-row segments (1 prefix load)
//   k_attn: SPLIT-K flash attention (<=16 key chunks/block), permlane
//           P-relayout, z-init MFMA, uniform diag branch, cvt_pk packing.
//           NOTE: r6 2-buffer __syncthreads loop kept deliberately —
//           r7's 3-buffer counted-vmcnt pipeline was null per-iter and
//           cost occupancy (48KB LDS); drain is NOT the per-iter cost.
//           launch_bounds(256,4); (256,5) caused scratch spills (r4).
//   k_comb: sums the two partials per long tile, normalizes, writes bf16
//   k_gemm_nt64: out = Obf @ Wo^T (BK=64, swizzled)
// ---------------------------------------------------------------------------

typedef unsigned short u16;
typedef __attribute__((ext_vector_type(8))) __bf16 bf16x8;
typedef __attribute__((ext_vector_type(4))) float f32x4;
typedef __attribute__((ext_vector_type(2))) unsigned int uint2v;

#define D_MODEL 1024
#define N_HEADS 16
#define BATCH   2
#define SEQ     2048
#define D_HEAD  64
#define ROWS    (BATCH*SEQ)   /* 4096 */
#define NSEG    64
#define SEGLEN  32
#define LOG2E   1.44269504f

static __device__ __forceinline__ u16 f2bf(float f){
  union { float f; uint32_t u; } v; v.f = f;
  uint32_t r = v.u + 0x7fffu + ((v.u >> 16) & 1u);
  return (u16)(r >> 16);
}
static __device__ __forceinline__ float bf2f(u16 h){
  union { uint32_t u; float f; } v; v.u = ((uint32_t)h) << 16;
  return v.f;
}
static __device__ __forceinline__ uint32_t cvtpk(float lo, float hi){
  uint32_t r;
  asm("v_cvt_pk_bf16_f32 %0, %1, %2" : "=v"(r) : "v"(lo), "v"(hi));
  return r;
}
#define GLDS(gp, lp) __builtin_amdgcn_global_load_lds( \
    (const __attribute__((address_space(1))) void*)(gp), \
    (__attribute__((address_space(3))) void*)(lp), 16, 0, 0)

// ------------------------- merged cast kernel ------------------------------
__global__ void k_cast_all(const float* __restrict__ X,
                           u16* __restrict__ Xhi, u16* __restrict__ Xlo,
                           const float* __restrict__ Wq,
                           u16* __restrict__ Wqh, u16* __restrict__ Wql,
                           const float* __restrict__ Wk,
                           u16* __restrict__ Wkh, u16* __restrict__ Wkl,
                           const float* __restrict__ Wv, u16* __restrict__ Wvb,
                           const float* __restrict__ Wo, u16* __restrict__ Wob){
  int i = blockIdx.x*256 + threadIdx.x;   // float4 index
  if (i < 1572864){                       // split: X | Wq | Wk
    const float* src; u16 *dh, *dl; int base;
    if (i < 1048576){ src = X;  dh = Xhi; dl = Xlo; base = i; }
    else if (i < 1310720){ src = Wq; dh = Wqh; dl = Wql; base = i - 1048576; }
    else { src = Wk; dh = Wkh; dl = Wkl; base = i - 1310720; }
    float4 v = reinterpret_cast<const float4*>(src)[base];
    float vs[4] = {v.x, v.y, v.z, v.w};
    union { u16 s[4]; uint2 u; } uh, ul;
#pragma unroll
    for (int r=0;r<4;++r){
      uh.s[r] = f2bf(vs[r]);
      ul.s[r] = f2bf(vs[r] - bf2f(uh.s[r]));
    }
    reinterpret_cast<uint2*>(dh)[base] = uh.u;
    reinterpret_cast<uint2*>(dl)[base] = ul.u;
  } else {                                // plain: Wv | Wo
    const float* src; u16* dst; int base;
    if (i < 1835008){ src = Wv; dst = Wvb; base = i - 1572864; }
    else { src = Wo; dst = Wob; base = i - 1835008; }
    float4 v = reinterpret_cast<const float4*>(src)[base];
    float vs[4] = {v.x, v.y, v.z, v.w};
    union { u16 s[4]; uint2 u; } uh;
#pragma unroll
    for (int r=0;r<4;++r) uh.s[r] = f2bf(vs[r]);
    reinterpret_cast<uint2*>(dst)[base] = uh.u;
  }
}

// ---- mega: XCD-partitioned longest-first: QK | VT | corr, BK=64 swizzled --
__global__ __launch_bounds__(256) void k_mega(
    const u16* __restrict__ Xhi, const u16* __restrict__ Xlo,
    const u16* __restrict__ Wh,  const u16* __restrict__ Wl,
    const u16* __restrict__ Wvb,
    float* __restrict__ C, float* __restrict__ Dlt, u16* __restrict__ Vt)
{
  __shared__ __align__(16) u16 smem[16384];   // 32 KB
  const int xj = blockIdx.x & 7, q = blockIdx.x >> 3;   // q: 0..143
  int section, idx;
  if (q < 64)      { section = 0; idx = xj*64 + q; }       // QK (longest, first)
  else if (q < 128){ section = 1; idx = xj*64 + (q-64); }  // VT
  else             { section = 2; idx = xj*16 + (q-128); } // corr (shortest)
  const int tid = threadIdx.x, wv = tid>>6, ln = tid&63;
  const int lane15 = ln&15, quad = ln>>4;
  const int wm = wv&1, wn = wv>>1;
  const int g = ln&7, sr = ln>>3;           // staging lane coords
  const int fs = lane15 & 7;                // fragment swizzle key
  f32x4 z = {0.f,0.f,0.f,0.f};
  u16* As = smem;                           // 128x64 (8192 u16)
  u16* Bs = smem + 8192;

  if (section == 2){
    // ---- head-0 correction: plane cz: Xhi@Wlo^T (cz=0) / Xlo@Whi^T (cz=1) -
    const int cx = idx & 1;             // Q / K col-group
    const int cy = (idx >> 1) & 31;     // row tile
    const int cz = idx >> 6;            // pass -> its own output plane
    const size_t rowBase = (size_t)cy*128;
    const size_t wbase = cx ? (size_t)1024*1024 : 0;
    const u16* Ap = cz ? Xlo : Xhi;
    const u16* Bp = (cz ? Wh : Wl) + wbase;
    f32x4 acc[4][2];
#pragma unroll
    for (int i=0;i<4;++i){ acc[i][0] = z; acc[i][1] = z; }
    for (int kt = 0; kt < 16; ++kt) {
      __syncthreads();
#pragma unroll
      for (int c = 0; c < 4; ++c) {
        int chunk = wv*4 + c, r = chunk*8 + sr;
        GLDS(Ap + (rowBase + r)*1024 + kt*64 + (g^sr)*8, As + chunk*512);
      }
#pragma unroll
      for (int c = 0; c < 2; ++c) {
        int chunk = wv*2 + c, r = chunk*8 + sr;
        GLDS(Bp + (size_t)r*1024 + kt*64 + (g^sr)*8, Bs + chunk*512);
      }
      __syncthreads();
#pragma unroll
      for (int k2=0;k2<2;++k2){
        bf16x8 af[4], bfb[2];
#pragma unroll
        for (int t=0;t<4;++t)
          af[t]  = *reinterpret_cast<const bf16x8*>(As + (wm*64 + t*16 + lane15)*64 + (((k2*4+quad)^fs)*8));
#pragma unroll
        for (int t=0;t<2;++t)
          bfb[t] = *reinterpret_cast<const bf16x8*>(Bs + (wn*32 + t*16 + lane15)*64 + (((k2*4+quad)^fs)*8));
#pragma unroll
        for (int i=0;i<4;++i)
#pragma unroll
          for (int j=0;j<2;++j)
            acc[i][j] = __builtin_amdgcn_mfma_f32_16x16x32_bf16(af[i], bfb[j], acc[i][j], 0,0,0);
      }
    }
    float* Dp = Dlt + (size_t)cz*ROWS*128;
#pragma unroll
    for (int i=0;i<4;++i){
      size_t row = rowBase + wm*64 + i*16 + quad*4;
#pragma unroll
      for (int j=0;j<2;++j){
        size_t col = (size_t)cx*64 + wn*32 + j*16 + lane15;
#pragma unroll
        for (int r=0;r<4;++r)
          Dp[(row+r)*128 + col] = acc[i][j][r];
      }
    }
  } else if (section == 0){
    // ---------------- QK projection: 128x128 tile, 1-pass ------------------
    const size_t rowBase = (size_t)(idx>>4)*128, colBase = (size_t)(idx&15)*128;
    f32x4 acc[4][4];
#pragma unroll
    for (int i=0;i<4;++i)
#pragma unroll
      for (int j=0;j<4;++j) acc[i][j] = z;
    for (int kt = 0; kt < 16; ++kt) {
      __syncthreads();
#pragma unroll
      for (int c = 0; c < 4; ++c) {
        int chunk = wv*4 + c, r = chunk*8 + sr;
        GLDS(Xhi + (rowBase + r)*1024 + kt*64 + (g^sr)*8, As + chunk*512);
        GLDS(Wh  + (colBase + r)*1024 + kt*64 + (g^sr)*8, Bs + chunk*512);
      }
      __syncthreads();
#pragma unroll
      for (int k2=0;k2<2;++k2){
        bf16x8 af[4], bfb[4];
#pragma unroll
        for (int t=0;t<4;++t){
          af[t]  = *reinterpret_cast<const bf16x8*>(As + (wm*64 + t*16 + lane15)*64 + (((k2*4+quad)^fs)*8));
          bfb[t] = *reinterpret_cast<const bf16x8*>(Bs + (wn*64 + t*16 + lane15)*64 + (((k2*4+quad)^fs)*8));
        }
#pragma unroll
        for (int i=0;i<4;++i)
#pragma unroll
          for (int j=0;j<4;++j)
            acc[i][j] = __builtin_amdgcn_mfma_f32_16x16x32_bf16(af[i], bfb[j], acc[i][j], 0,0,0);
      }
    }
#pragma unroll
    for (int i=0;i<4;++i){
      size_t row = rowBase + wm*64 + i*16 + quad*4;
#pragma unroll
      for (int j=0;j<4;++j){
        size_t col = colBase + wn*64 + j*16 + lane15;
#pragma unroll
        for (int r=0;r<4;++r)
          C[(row+r)*2048 + col] = acc[i][j][r];
      }
    }
  } else {
    // ------- V projection with fused V^T bf16 epilogue (LDS transpose) -----
    const int bx = idx & 15, by = idx >> 4;
    const size_t rowBase = (size_t)by*128, colBase = (size_t)bx*64;
    f32x4 acc[4][2];
#pragma unroll
    for (int i=0;i<4;++i){ acc[i][0] = z; acc[i][1] = z; }
    for (int kt = 0; kt < 16; ++kt) {
      __syncthreads();
#pragma unroll
      for (int c = 0; c < 4; ++c) {
        int chunk = wv*4 + c, r = chunk*8 + sr;
        GLDS(Xhi + (rowBase + r)*1024 + kt*64 + (g^sr)*8, As + chunk*512);
      }
#pragma unroll
      for (int c = 0; c < 2; ++c) {
        int chunk = wv*2 + c, r = chunk*8 + sr;
        GLDS(Wvb + (colBase + r)*1024 + kt*64 + (g^sr)*8, Bs + chunk*512);
      }
      __syncthreads();
#pragma unroll
      for (int k2=0;k2<2;++k2){
        bf16x8 af[4], bfb[2];
#pragma unroll
        for (int t=0;t<4;++t)
          af[t]  = *reinterpret_cast<const bf16x8*>(As + (wm*64 + t*16 + lane15)*64 + (((k2*4+quad)^fs)*8));
#pragma unroll
        for (int t=0;t<2;++t)
          bfb[t] = *reinterpret_cast<const bf16x8*>(Bs + (wn*32 + t*16 + lane15)*64 + (((k2*4+quad)^fs)*8));
#pragma unroll
        for (int i=0;i<4;++i)
#pragma unroll
          for (int j=0;j<2;++j)
            acc[i][j] = __builtin_amdgcn_mfma_f32_16x16x32_bf16(af[i], bfb[j], acc[i][j], 0,0,0);
      }
    }
    // transpose epilogue: stage bf16 tile as [d 64][n 128] (stride 136)
    __syncthreads();
#pragma unroll
    for (int i=0;i<4;++i){
      int nl = wm*64 + i*16 + quad*4;
#pragma unroll
      for (int j=0;j<2;++j){
        int dl = wn*32 + j*16 + lane15;
#pragma unroll
        for (int r=0;r<4;++r)
          smem[dl*136 + nl + r] = f2bf(acc[i][j][r]);
      }
    }
    __syncthreads();
    const int b = by >> 4;
    const int n0 = (by & 15) * 128;
    const int bh = b*N_HEADS + bx;
    const int d = tid >> 2, seg = tid & 3;
    u16* dst = Vt + ((size_t)(bh*64 + d))*SEQ + n0 + seg*32;
    const u16* srcl = smem + d*136 + seg*32;
#pragma unroll
    for (int k=0;k<4;++k)
      *reinterpret_cast<uint4*>(dst + k*8) = *reinterpret_cast<const uint4*>(srcl + k*8);
  }
}

// --------- merged LN for Q and K + bf16 head packs (+ head0 corr) ----------
__global__ __launch_bounds__(256) void k_ln_pack2(
    const float* __restrict__ C, const float* __restrict__ Dlt,
    const float* __restrict__ gq, const float* __restrict__ bq,
    const float* __restrict__ gk, const float* __restrict__ bk,
    u16* __restrict__ Qh, u16* __restrict__ Kh,
    u16* __restrict__ Q0l, u16* __restrict__ K0l)
{
  const int row = blockIdx.x;
  const int tid = threadIdx.x;
  const float* cr = C + (size_t)row*2048;
  float4 vq = reinterpret_cast<const float4*>(cr)[tid];
  float4 vk = reinterpret_cast<const float4*>(cr)[256 + tid];
  const int h = tid >> 4;
  if (h == 0){
    const float* D0 = Dlt + (size_t)row*128;
    const float* D1 = Dlt + (size_t)ROWS*128 + (size_t)row*128;
    float4 a0 = reinterpret_cast<const float4*>(D0)[tid&15];
    float4 a1 = reinterpret_cast<const float4*>(D1)[tid&15];
    vq.x+=a0.x+a1.x; vq.y+=a0.y+a1.y; vq.z+=a0.z+a1.z; vq.w+=a0.w+a1.w;
    float4 b0 = reinterpret_cast<const float4*>(D0 + 64)[tid&15];
    float4 b1 = reinterpret_cast<const float4*>(D1 + 64)[tid&15];
    vk.x+=b0.x+b1.x; vk.y+=b0.y+b1.y; vk.z+=b0.z+b1.z; vk.w+=b0.w+b1.w;
  }
  float sq  = vq.x+vq.y+vq.z+vq.w;
  float s2q = vq.x*vq.x+vq.y*vq.y+vq.z*vq.z+vq.w*vq.w;
  float sk  = vk.x+vk.y+vk.z+vk.w;
  float s2k = vk.x*vk.x+vk.y*vk.y+vk.z*vk.z+vk.w*vk.w;
#pragma unroll
  for (int o=32;o;o>>=1){
    sq += __shfl_xor(sq,o);  s2q += __shfl_xor(s2q,o);
    sk += __shfl_xor(sk,o);  s2k += __shfl_xor(s2k,o);
  }
  __shared__ float red[4][4];
  if ((tid&63)==0){
    red[tid>>6][0]=sq; red[tid>>6][1]=s2q; red[tid>>6][2]=sk; red[tid>>6][3]=s2k;
  }
  __syncthreads();
  sq  = red[0][0]+red[1][0]+red[2][0]+red[3][0];
  s2q = red[0][1]+red[1][1]+red[2][1]+red[3][1];
  sk  = red[0][2]+red[1][2]+red[2][2]+red[3][2];
  s2k = red[0][3]+red[1][3]+red[2][3]+red[3][3];
  const float muq = sq*(1.f/D_MODEL);
  const float rsq = rsqrtf(s2q*(1.f/D_MODEL) - muq*muq + 1e-5f);
  const float muk = sk*(1.f/D_MODEL);
  const float rsk = rsqrtf(s2k*(1.f/D_MODEL) - muk*muk + 1e-5f);
  const int b = row >> 11, n = row & (SEQ-1);
  const int d0 = (tid & 15)*4;
  float4 gqv = reinterpret_cast<const float4*>(gq)[tid];
  float4 bqv = reinterpret_cast<const float4*>(bq)[tid];
  float4 gkv = reinterpret_cast<const float4*>(gk)[tid];
  float4 bkv = reinterpret_cast<const float4*>(bk)[tid];
  float xq[4] = {vq.x,vq.y,vq.z,vq.w}, xk[4] = {vk.x,vk.y,vk.z,vk.w};
  float gQ[4] = {gqv.x,gqv.y,gqv.z,gqv.w}, bQ[4] = {bqv.x,bqv.y,bqv.z,bqv.w};
  float gK[4] = {gkv.x,gkv.y,gkv.z,gkv.w}, bK[4] = {bkv.x,bkv.y,bkv.z,bkv.w};
  union { u16 s[4]; uint2 u; } qh, ql, kh, kl;
#pragma unroll
  for (int r=0;r<4;++r){
    float yq = (xq[r]-muq)*rsq*gQ[r] + bQ[r];
    qh.s[r] = f2bf(yq);
    ql.s[r] = f2bf(yq - bf2f(qh.s[r]));
    float yk = (xk[r]-muk)*rsk*gK[r] + bK[r];
    kh.s[r] = f2bf(yk);
    kl.s[r] = f2bf(yk - bf2f(kh.s[r]));
  }
  size_t dst = (((size_t)(b*N_HEADS + h))*SEQ + n)*D_HEAD + d0;
  *reinterpret_cast<uint2*>(Qh + dst) = qh.u;
  *reinterpret_cast<uint2*>(Kh + dst) = kh.u;
  if (h == 0){
    size_t dl = ((size_t)b*SEQ + n)*D_HEAD + d0;
    *reinterpret_cast<uint2*>(Q0l + dl) = ql.u;
    *reinterpret_cast<uint2*>(K0l + dl) = kl.u;
  }
}

// ------ head-0 scores, single-staged 4-tile LDS + 32-row segment sums ------
__global__ __launch_bounds__(256) void k_s0(
    const u16* Qh, const u16* Q0l, const u16* Kh, const u16* K0l,
    float* __restrict__ S0, float* __restrict__ seg)
{
  const int b = blockIdx.z;
  const int bm = blockIdx.y;  // j (query-row) 128-tile -> segments 4bm..4bm+3
  const int bn = blockIdx.x;  // m (key-col) tile
  const int tid = threadIdx.x;
  if (bn > bm){               // above diagonal: S never read there; seg = 0
    for (int t = tid; t < 512; t += 256)
      seg[((size_t)b*NSEG + bm*4 + (t>>7))*SEQ + bn*128 + (t&127)] = 0.f;
    return;
  }
  float* Sb = S0 + (size_t)b*SEQ*SEQ;
  __shared__ __align__(16) u16 smem[4*8192];   // Qhi|Qlo|Khi|Klo, 64 KB
  const int wv = tid>>6, ln = tid&63;
  const int lane15 = ln&15, quad = ln>>4;
  const int wm = wv&1, wn = wv>>1;
  const int g = ln&7, sr = ln>>3;
  const int fs = lane15 & 7;
  const size_t rowBase = (size_t)bm*128, colBase = (size_t)bn*128;
  const u16* srcs[4] = {
    Qh  + ((size_t)b*N_HEADS*SEQ + rowBase)*D_HEAD,   // head-0 Q hi
    Q0l + ((size_t)b*SEQ + rowBase)*D_HEAD,
    Kh  + ((size_t)b*N_HEADS*SEQ + colBase)*D_HEAD,   // head-0 K hi
    K0l + ((size_t)b*SEQ + colBase)*D_HEAD };
#pragma unroll
  for (int t=0;t<4;++t){
#pragma unroll
    for (int c=0;c<4;++c){
      int chunk = wv*4 + c, r = chunk*8 + sr;
      GLDS(srcs[t] + (size_t)r*64 + (g^sr)*8, smem + t*8192 + chunk*512);
    }
  }
  __syncthreads();
  f32x4 acc[4][4];
  f32x4 z = {0.f,0.f,0.f,0.f};
#pragma unroll
  for (int i=0;i<4;++i)
#pragma unroll
    for (int j=0;j<4;++j) acc[i][j] = z;
  const int Aidx[3] = {0, 0, 1};    // Qhi,Qhi,Qlo
  const int Bidx[3] = {2, 3, 2};    // Khi,Klo,Khi
#pragma unroll
  for (int p = 0; p < 3; ++p){
    const u16* At = smem + Aidx[p]*8192;
    const u16* Bt = smem + Bidx[p]*8192;
#pragma unroll
    for (int k2=0;k2<2;++k2){
      bf16x8 af[4], bfb[4];
#pragma unroll
      for (int t=0;t<4;++t){
        af[t]  = *reinterpret_cast<const bf16x8*>(At + (wm*64 + t*16 + lane15)*64 + (((k2*4+quad)^fs)*8));
        bfb[t] = *reinterpret_cast<const bf16x8*>(Bt + (wn*64 + t*16 + lane15)*64 + (((k2*4+quad)^fs)*8));
      }
#pragma unroll
      for (int i=0;i<4;++i)
#pragma unroll
        for (int j=0;j<4;++j)
          acc[i][j] = __builtin_amdgcn_mfma_f32_16x16x32_bf16(af[i], bfb[j], acc[i][j], 0,0,0);
    }
  }
  float csum[2][4] = {{0.f,0.f,0.f,0.f},{0.f,0.f,0.f,0.f}};
#pragma unroll
  for (int i=0;i<4;++i){
#pragma unroll
    for (int j=0;j<4;++j){
#pragma unroll
      for (int r=0;r<4;++r){
        int jg = (int)rowBase + wm*64 + i*16 + quad*4 + r;
        int mg = (int)colBase + wn*64 + j*16 + lane15;
        float l = acc[i][j][r]*0.125f;
        float s = (mg >= 1 && mg < jg) ? fmaxf(l, 0.f) : 0.f;
        Sb[(size_t)jg*SEQ + mg] = s;
        csum[i>>1][j] += s;
      }
    }
  }
  __syncthreads();                 // tiles consumed; reuse LDS for cs
  float* cs = (float*)smem;        // [4][128]
#pragma unroll
  for (int h2=0;h2<2;++h2){
#pragma unroll
    for (int j=0;j<4;++j){
      float v = csum[h2][j];
      v += __shfl_xor(v, 16);
      v += __shfl_xor(v, 32);
      if (ln < 16) cs[(wm*2 + h2)*128 + wn*64 + j*16 + ln] = v;
    }
  }
  __syncthreads();
  for (int t = tid; t < 512; t += 256)
    seg[((size_t)b*NSEG + bm*4 + (t>>7))*SEQ + bn*128 + (t&127)] = cs[t];
}

// --- in-place exclusive prefix over Seg's 64 s-slices, per column ----------
// After this, seg[s][m] = sum_{t<s} seg_orig[t][m]; k_seg_apply does 1 load.
__global__ void k_segpfx(float* __restrict__ seg){
  const int gidx = blockIdx.x*256 + threadIdx.x;   // 0..4095
  const int b = gidx >> 11, m = gidx & (SEQ-1);
  float* col = seg + (size_t)b*NSEG*SEQ + m;
  float run = 0.f;
#pragma unroll
  for (int s=0; s<NSEG; ++s){
    float v = col[(size_t)s*SEQ];
    col[(size_t)s*SEQ] = run;
    run += v;
  }
}

// --- in place: S -> -F*log2e; 32-row segments; prefix from k_segpfx --------
__global__ void k_seg_apply(float* __restrict__ SF, const float* __restrict__ seg){
  int m = blockIdx.x*256 + threadIdx.x;
  int s = blockIdx.y, b = blockIdx.z;
  float run = seg[((size_t)b*NSEG + s)*SEQ + m];   // exclusive prefix, 1 load
  float* Sb = SF + (size_t)b*SEQ*SEQ;
  const int j0 = s*SEGLEN;
#pragma unroll 8
  for (int i=0;i<SEGLEN;++i){
    size_t idx = (size_t)(j0 + i)*SEQ + m;
    float t = Sb[idx];
    Sb[idx] = -run*LOG2E;
    run += (j0 + i > m) ? t : 0.f;
  }
}

// ------------- split-K flash attention, fixed-max softmax ------------------
// Work item table (per bh): 48 entries sorted by length descending.
// code < 64: long tile, nt = code>>1 (16..31), seg = code&1, key range split
//            at half = (nt+2)>>1; writes f32 partials (exact-additive since
//            softmax offset F is fixed per row, no running max).
// code >= 64: short tile nt = code-64 (0..15), full range, direct bf16 write.
__constant__ unsigned char WMAP[48] = {
  62,63,60,79,
  61,58,59,56,78,
  57,54,55,52,77,
  53,50,51,48,76,
  49,46,47,44,75,
  45,42,43,40,74,
  41,38,39,36,73,
  37,34,35,32,72,
  33,71,
  70,69,68,67,66,65,64};

__global__ __launch_bounds__(256, 4) void k_attn(
    const u16* __restrict__ Qh, const u16* __restrict__ Kh,
    const u16* __restrict__ Vt, const float* __restrict__ F,
    u16* __restrict__ Ob, float* __restrict__ Opart, float* __restrict__ Ps)
{
  __shared__ __align__(16) u16 Ks[2][64*64];
  __shared__ __align__(16) u16 Vs[2][64*64];
  const int w = blockIdx.x;
  const int bh = w & 31, b = bh >> 4, h = bh & 15;
  const int item = (int)WMAP[w >> 5];
  int nt, mt0, mt1, segi;
  if (item >= 64){ nt = item - 64; segi = 0; mt0 = 0; mt1 = nt; }
  else {
    nt = item >> 1; segi = item & 1;
    const int half = (nt + 2) >> 1;           // ceil((nt+1)/2)
    mt0 = segi ? half : 0;
    mt1 = segi ? nt : (half - 1);
  }
  const bool partial = (item < 64);
  const int tid = threadIdx.x, wv = tid>>6, ln = tid&63;
  const int lane15 = ln&15, quad = ln>>4;
  const u16* Qbh = Qh + ((size_t)(b*N_HEADS + h))*SEQ*D_HEAD;
  const u16* Kbh = Kh + ((size_t)(b*N_HEADS + h))*SEQ*D_HEAD;
  const u16* Vbh = Vt + ((size_t)(b*N_HEADS + h))*D_HEAD*SEQ;
  const int n_loc = wv*16 + lane15;
  const int n_g = nt*64 + n_loc;
  const float* Frow = F + (size_t)b*SEQ*SEQ + (size_t)n_g*SEQ;
  const int swz = (ln&7) ^ ((ln>>3)&7);
  const int fswz = lane15 & 7;
  const int srow = ln>>3;

  bf16x8 qf[2];
#pragma unroll
  for (int kt=0; kt<2; ++kt)
    qf[kt] = *reinterpret_cast<const bf16x8*>(Qbh + (size_t)n_g*D_HEAD + kt*32 + quad*8);

  f32x4 z = {0.f,0.f,0.f,0.f};
  f32x4 psum = z;
  f32x4 acc_o[4];
#pragma unroll
  for (int no=0;no<4;++no) acc_o[no] = z;

  auto stage = [&](int mt, int buf){
#pragma unroll
    for (int c=0;c<2;++c){
      int chunk = wv*2 + c;
      int r = chunk*8 + srow;
      GLDS(Kbh + (size_t)(mt*64 + r)*D_HEAD + swz*8, &Ks[buf][chunk*512]);
      GLDS(Vbh + (size_t)r*SEQ + mt*64 + swz*8,      &Vs[buf][chunk*512]);
    }
  };
  stage(mt0, mt0 & 1);
  // preload F for first chunk (already stored as -F*log2e)
  f32x4 fvn[4];
#pragma unroll
  for (int ms=0; ms<4; ++ms)
    fvn[ms] = *reinterpret_cast<const f32x4*>(Frow + mt0*64 + ms*16 + quad*4);
  const float c1 = 0.125f*LOG2E;

  for (int mt = mt0; mt <= mt1; ++mt) {
    const int cur = mt & 1;
    __syncthreads();                    // drain: buf[cur] ready
    if (mt < mt1) stage(mt+1, 1-cur);   // prefetch next K/V chunk
    f32x4 fv[4];
#pragma unroll
    for (int ms=0; ms<4; ++ms) fv[ms] = fvn[ms];
    if (mt < mt1){                      // prefetch next F chunk into registers
      const float* Fr1 = Frow + (mt+1)*64;
#pragma unroll
      for (int ms=0; ms<4; ++ms)
        fvn[ms] = *reinterpret_cast<const f32x4*>(Fr1 + ms*16 + quad*4);
    }
    // S^T chunk: rows m (4 x 16), col n = lane15. kt=0 seeds with C=z
    // (saves the 16-mov accumulator zero-init).
    f32x4 accs[4];
    __builtin_amdgcn_s_setprio(1);
#pragma unroll
    for (int ms=0; ms<4; ++ms){
      bf16x8 a = *reinterpret_cast<const bf16x8*>(
          &Ks[cur][(ms*16 + lane15)*64 + ((quad ^ fswz) * 8)]);
      accs[ms] = __builtin_amdgcn_mfma_f32_16x16x32_bf16(a, qf[0], z, 0,0,0);
    }
#pragma unroll
    for (int ms=0; ms<4; ++ms){
      bf16x8 a = *reinterpret_cast<const bf16x8*>(
          &Ks[cur][(ms*16 + lane15)*64 + (((4 + quad) ^ fswz) * 8)]);
      accs[ms] = __builtin_amdgcn_mfma_f32_16x16x32_bf16(a, qf[1], accs[ms], 0,0,0);
    }
    __builtin_amdgcn_s_setprio(0);
    // fixed-max softmax: p = exp2(score*log2e - F*log2e)
    // Two block-uniform variants keep per-ms live ranges small (no spills).
    uint32_t pw[4][2];
    if (mt == nt){
#pragma unroll
      for (int ms=0; ms<4; ++ms){
        const int ml = ms*16 + quad*4;
        float l0 = fmaf(accs[ms][0], c1, fv[ms][0]);
        float l1 = fmaf(accs[ms][1], c1, fv[ms][1]);
        float l2 = fmaf(accs[ms][2], c1, fv[ms][2]);
        float l3 = fmaf(accs[ms][3], c1, fv[ms][3]);
        if (ml + 0 > n_loc) l0 = -1e30f;
        if (ml + 1 > n_loc) l1 = -1e30f;
        if (ml + 2 > n_loc) l2 = -1e30f;
        if (ml + 3 > n_loc) l3 = -1e30f;
        float p0 = __builtin_amdgcn_exp2f(l0);
        float p1 = __builtin_amdgcn_exp2f(l1);
        float p2 = __builtin_amdgcn_exp2f(l2);
        float p3 = __builtin_amdgcn_exp2f(l3);
        psum[0]+=p0; psum[1]+=p1; psum[2]+=p2; psum[3]+=p3;
        pw[ms][0] = cvtpk(p0, p1);
        pw[ms][1] = cvtpk(p2, p3);
      }
    } else {
#pragma unroll
      for (int ms=0; ms<4; ++ms){
        float p0 = __builtin_amdgcn_exp2f(fmaf(accs[ms][0], c1, fv[ms][0]));
        float p1 = __builtin_amdgcn_exp2f(fmaf(accs[ms][1], c1, fv[ms][1]));
        float p2 = __builtin_amdgcn_exp2f(fmaf(accs[ms][2], c1, fv[ms][2]));
        float p3 = __builtin_amdgcn_exp2f(fmaf(accs[ms][3], c1, fv[ms][3]));
        psum[0]+=p0; psum[1]+=p1; psum[2]+=p2; psum[3]+=p3;
        pw[ms][0] = cvtpk(p0, p1);
        pw[ms][1] = cvtpk(p2, p3);
      }
    }
    // P relayout: C-layout (m=quad*4+r) -> A-fragment (k=quad*8+j) via
    // permlane32_swap + permlane16_swap (VALU cross-lane, no LDS traffic).
    __builtin_amdgcn_s_setprio(1);
#pragma unroll
    for (int kt=0; kt<2; ++kt){
      union { uint32_t u[4]; bf16x8 v; } pa;
#pragma unroll
      for (int pr=0; pr<2; ++pr){
        uint2v s32 = __builtin_amdgcn_permlane32_swap(
            pw[2*kt][pr], pw[2*kt+1][pr], false, false);
        uint2v s16 = __builtin_amdgcn_permlane16_swap(s32.x, s32.y, false, false);
        pa.u[pr]   = s16.x;
        pa.u[2+pr] = s16.y;
      }
#pragma unroll
      for (int no=0; no<4; ++no){
        int d = no*16 + lane15;
        bf16x8 vb = *reinterpret_cast<const bf16x8*>(
            &Vs[cur][d*64 + (((kt*4 + quad) ^ (d&7)) * 8)]);
        acc_o[no] = __builtin_amdgcn_mfma_f32_16x16x32_bf16(pa.v, vb, acc_o[no], 0,0,0);
      }
    }
    __builtin_amdgcn_s_setprio(0);
  }
  float s = (psum[0]+psum[1]) + (psum[2]+psum[3]);
  s += __shfl_xor(s, 16);
  s += __shfl_xor(s, 32);
  if (partial){
    // exact-additive partial: raw acc_o (f32) + per-row psum
    const size_t pb = (size_t)(bh*16 + (nt - 16))*2 + segi;
    float* Op = Opart + pb*4096;
    if (quad == 0) Ps[pb*64 + wv*16 + lane15] = s;
#pragma unroll
    for (int no=0; no<4; ++no)
#pragma unroll
      for (int r=0;r<4;++r)
        Op[(wv*16 + quad*4 + r)*64 + no*16 + lane15] = acc_o[no][r];
  } else {
    f32x4 inv;
#pragma unroll
    for (int r=0;r<4;++r)
      inv[r] = __builtin_amdgcn_rcpf(__shfl(s, quad*4 + r));
#pragma unroll
    for (int no=0; no<4; ++no){
#pragma unroll
      for (int r=0;r<4;++r){
        float o = acc_o[no][r] * inv[r];
        int row = nt*64 + wv*16 + quad*4 + r;
        Ob[((size_t)(b*SEQ + row))*D_MODEL + h*64 + no*16 + lane15] = f2bf(o);
      }
    }
  }
}

// --------- combine two key-segment partials per long tile -> bf16 ----------
__global__ __launch_bounds__(256) void k_comb(
    const float* __restrict__ Opart, const float* __restrict__ Ps,
    u16* __restrict__ Ob)
{
  const int t = blockIdx.x;            // bh*16 + (nt-16), 0..511
  const int bh = t >> 4, b = bh >> 4, h = bh & 15;
  const int nt = (t & 15) + 16;
  const int tid = threadIdx.x;
  const int row = tid >> 2, c0 = (tid & 3) * 16;
  const float* P0 = Opart + (size_t)t*2*4096 + row*64 + c0;
  const float* P1 = P0 + 4096;
  const float s = Ps[(size_t)t*128 + row] + Ps[(size_t)t*128 + 64 + row];
  const float inv = __builtin_amdgcn_rcpf(s);
  union { u16 us[16]; uint4 u[2]; } o;
#pragma unroll
  for (int g2=0; g2<4; ++g2){
    float4 a = reinterpret_cast<const float4*>(P0)[g2];
    float4 c = reinterpret_cast<const float4*>(P1)[g2];
    o.us[g2*4+0] = f2bf((a.x + c.x) * inv);
    o.us[g2*4+1] = f2bf((a.y + c.y) * inv);
    o.us[g2*4+2] = f2bf((a.z + c.z) * inv);
    o.us[g2*4+3] = f2bf((a.w + c.w) * inv);
  }
  u16* dst = Ob + ((size_t)(b*SEQ + nt*64 + row))*D_MODEL + h*64 + c0;
  reinterpret_cast<uint4*>(dst)[0] = o.u[0];
  reinterpret_cast<uint4*>(dst)[1] = o.u[1];
}

// ------------- NT GEMM, 128x64 tile, BK=64 swizzled (O-proj) ---------------
__global__ __launch_bounds__(256) void k_gemm_nt64(
    const u16* __restrict__ A0, const u16* __restrict__ B0,
    float* __restrict__ C, int N, int K)
{
  __shared__ __align__(16) u16 As[8192];   // 128x64
  __shared__ __align__(16) u16 Bs[4096];   // 64x64
  const int tid = threadIdx.x, wv = tid>>6, ln = tid&63;
  const int lane15 = ln&15, quad = ln>>4;
  const int wm = wv&1, wn = wv>>1;
  const int g = ln&7, sr = ln>>3;
  const int fs = lane15 & 7;
  const size_t rowBase = (size_t)blockIdx.y*128, colBase = (size_t)blockIdx.x*64;
  f32x4 acc[4][2];
  f32x4 z = {0.f,0.f,0.f,0.f};
#pragma unroll
  for (int i=0;i<4;++i){ acc[i][0] = z; acc[i][1] = z; }
  const int ktiles = K >> 6;
  for (int kt = 0; kt < ktiles; ++kt) {
    __syncthreads();
#pragma unroll
    for (int c = 0; c < 4; ++c) {
      int chunk = wv*4 + c, r = chunk*8 + sr;
      GLDS(A0 + (rowBase + r)*K + kt*64 + (g^sr)*8, As + chunk*512);
    }
#pragma unroll
    for (int c = 0; c < 2; ++c) {
      int chunk = wv*2 + c, r = chunk*8 + sr;
      GLDS(B0 + (colBase + r)*K + kt*64 + (g^sr)*8, Bs + chunk*512);
    }
    __syncthreads();
#pragma unroll
    for (int k2=0;k2<2;++k2){
      bf16x8 af[4], bfb[2];
#pragma unroll
      for (int t=0;t<4;++t)
        af[t]  = *reinterpret_cast<const bf16x8*>(As + (wm*64 + t*16 + lane15)*64 + (((k2*4+quad)^fs)*8));
#pragma unroll
      for (int t=0;t<2;++t)
        bfb[t] = *reinterpret_cast<const bf16x8*>(Bs + (wn*32 + t*16 + lane15)*64 + (((k2*4+quad)^fs)*8));
#pragma unroll
      for (int i=0;i<4;++i)
#pragma unroll
        for (int j=0;j<2;++j)
          acc[i][j] = __builtin_amdgcn_mfma_f32_16x16x32_bf16(af[i], bfb[j], acc[i][j], 0,0,0);
    }
  }
#pragma unroll
  for (int i=0;i<4;++i){
    size_t row = rowBase + wm*64 + i*16 + quad*4;
#pragma unroll
    for (int j=0;j<2;++j){
      size_t col = colBase + wn*32 + j*16 + lane15;
#pragma unroll
      for (int r=0;r<4;++r)
        C[(row+r)*N + col] = acc[i][j][r];
    }
  }
}

// ------------------------------- launcher ----------------------------------
extern "C" void kernel_launch(void* const* d_in, const int* in_sizes, int n_in,
                              void* d_out, int out_size, void* d_ws, size_t ws_size,
                              hipStream_t stream)
{
  (void)in_sizes; (void)n_in; (void)out_size; (void)ws_size;
  const float* X  = (const float*)d_in[0];
  const float* Wq = (const float*)d_in[1];
  const float* Wk = (const float*)d_in[2];
  const float* Wv = (const float*)d_in[3];
  const float* Wo = (const float*)d_in[4];
  const float* gq = (const float*)d_in[5];
  const float* bq = (const float*)d_in[6];
  const float* gk = (const float*)d_in[7];
  const float* bk = (const float*)d_in[8];
  float* out = (float*)d_out;

  char* ws = (char*)d_ws;
  size_t off = 0;
  auto alloc = [&](size_t bytes)->char*{
    char* p = ws + off; off += (bytes + 255) & ~(size_t)255; return p;
  };
  u16* Xhi  = (u16*)alloc((size_t)ROWS*D_MODEL*2);
  u16* Xlo  = (u16*)alloc((size_t)ROWS*D_MODEL*2);
  u16* Wqkh = (u16*)alloc((size_t)2*D_MODEL*D_MODEL*2);  // [Wq;Wk] hi
  u16* Wqkl = (u16*)alloc((size_t)2*D_MODEL*D_MODEL*2);  // [Wq;Wk] lo
  u16* Wvb  = (u16*)alloc((size_t)D_MODEL*D_MODEL*2);
  u16* Wob  = (u16*)alloc((size_t)D_MODEL*D_MODEL*2);
  u16* Qhp  = (u16*)alloc((size_t)BATCH*N_HEADS*SEQ*D_HEAD*2);
  u16* Khp  = (u16*)alloc((size_t)BATCH*N_HEADS*SEQ*D_HEAD*2);
  u16* Q0l  = (u16*)alloc((size_t)BATCH*SEQ*D_HEAD*2);
  u16* K0l  = (u16*)alloc((size_t)BATCH*SEQ*D_HEAD*2);
  u16* Vtp  = (u16*)alloc((size_t)BATCH*N_HEADS*D_HEAD*SEQ*2);
  u16* Obf  = (u16*)alloc((size_t)ROWS*D_MODEL*2);
  float* Dlt = (float*)alloc((size_t)2*ROWS*128*4);      // head-0 corr planes
  float* Seg = (float*)alloc((size_t)BATCH*NSEG*SEQ*4);  // 1 MB
  float* Opart = (float*)alloc((size_t)512*2*4096*4);    // 16.8 MB partial O
  float* Ps    = (float*)alloc((size_t)512*2*64*4);      // partial psums
  float* SF  = (float*)alloc((size_t)BATCH*SEQ*SEQ*4);   // 33.5 MB
  float* C32 = SF;    // QK-proj fp32 scratch aliases SF (consumed before s0)

  k_cast_all<<<8192, 256, 0, stream>>>(
      X, Xhi, Xlo,
      Wq, Wqkh, Wqkl,
      Wk, Wqkh + (size_t)D_MODEL*D_MODEL, Wqkl + (size_t)D_MODEL*D_MODEL,
      Wv, Wvb, Wo, Wob);
  k_mega<<<1152, 256, 0, stream>>>(Xhi, Xlo, Wqkh, Wqkl, Wvb, C32, Dlt, Vtp);
  k_ln_pack2<<<ROWS, 256, 0, stream>>>(C32, Dlt, gq, bq, gk, bk, Qhp, Khp, Q0l, K0l);
  k_s0<<<dim3(16, 16, BATCH), 256, 0, stream>>>(Qhp, Q0l, Khp, K0l, SF, Seg);
  k_segpfx<<<16, 256, 0, stream>>>(Seg);
  k_seg_apply<<<dim3(8, NSEG, BATCH), 256, 0, stream>>>(SF, Seg);
  k_attn<<<1536, 256, 0, stream>>>(Qhp, Khp, Vtp, SF, Obf, Opart, Ps);
  k_comb<<<512, 256, 0, stream>>>(Opart, Ps, Obf);
  k_gemm_nt64<<<dim3(16, 32), 256, 0, stream>>>(Obf, Wob, out, D_MODEL, D_MODEL);
}